// Round 4
// baseline (99.911 us; speedup 1.0000x reference)
//
#include <hip/hip_runtime.h>
#include <hip/hip_cooperative_groups.h>

namespace cg = cooperative_groups;

// ---------------------------------------------------------------------------
// tNet, single cooperative kernel.
//   t5[z,d,r,t] = sum_{a,b,c,e,p,q,s} x[z,a,b,c] u1[a,d,e] b2[e,p,q]
//                                     u2[b,r,p] b1c[q,s] u3[c,t,s]
//   o = d*128+r*16+t ; i = a*128+b*16+c
// Phase A (per block, 4 W-rows each, non-redundant):
//   C2[e,p,s]=sum_q b2*b1c ; T1[a,p,s]=sum_e u1[a8+d]*C2 (d fixed per block);
//   T2[ab,s]=sum_p T1*u2 (r fixed) ; W[o,i]=sum_s T2*u3  -> bf16 global.
//   Also out[z][j] = fc2_b[j].
// grid.sync()
// Phase B: H-tile = relu(X@W^T + bias1) via bf16 MFMA (64x64, BK=128,
//   4 waves 2x2, reg-prefetch dbuf), then fused fc2 partials -> atomicAdd.
// ---------------------------------------------------------------------------

using s16x8 = __attribute__((ext_vector_type(8))) short;   // 8 bf16
using f32x4 = __attribute__((ext_vector_type(4))) float;

__device__ inline short f2bf(float f) {
    unsigned u = __builtin_bit_cast(unsigned, f);
    u += 0x7fffu + ((u >> 16) & 1u);          // round-to-nearest-even
    return (short)(u >> 16);
}

#define LDK 136

__global__ __launch_bounds__(256) void k_fused(
    const float* __restrict__ x, const float* __restrict__ u1,
    const float* __restrict__ u2, const float* __restrict__ u3,
    const float* __restrict__ b2, const float* __restrict__ b1c,
    const float* __restrict__ bias1, const float* __restrict__ fc2w,
    const float* __restrict__ fc2b, short* __restrict__ Wb,
    float* __restrict__ out) {
    __shared__ short As[64][LDK];              // 17408 B
    __shared__ short Bs[64][LDK];              // 17408 B
    __shared__ float W2s[10][64];
    const int tid = threadIdx.x;
    const int blk = blockIdx.x;

    // ================= Phase A: build 4 rows of W, init out ================
    {
        float* C2f = (float*)As;               // 4096 f32 (16 KB)  [alias]
        float* T1s = (float*)Bs;               // 2048 f32 (8 KB)   [alias]
        float* T2s = ((float*)Bs) + 2048;      // 64*17 f32 (4.25 KB)
        const int d = blk >> 5;
        const int r = (blk >> 2) & 7;
        const int t0 = (blk & 3) * 4;

        if (tid < 40) {                        // out init: 256 blk * 40 = 10240
            int idx = blk * 40 + tid;
            out[idx] = fc2b[idx % 10];
        }
        // C2[e,p,s]
#pragma unroll
        for (int j = 0; j < 16; ++j) {
            int idx = tid + 256 * j;
            int p = (idx >> 4) & 15, s = idx & 15;
            float acc = 0.f;
#pragma unroll
            for (int q = 0; q < 16; ++q)
                acc += b2[j * 256 + p * 16 + q] * b1c[q * 16 + s];
            C2f[idx] = acc;
        }
        __syncthreads();
        // T1[a][p*16+s], a = j  (d fixed)
#pragma unroll
        for (int j = 0; j < 8; ++j) {
            float acc = 0.f;
#pragma unroll
            for (int e = 0; e < 16; ++e)
                acc += u1[(j * 8 + d) * 16 + e] * C2f[e * 256 + tid];
            T1s[j * 256 + tid] = acc;
        }
        __syncthreads();
        // T2[ab][s] (r fixed), stride-17 to kill bank conflicts
#pragma unroll
        for (int j = 0; j < 4; ++j) {
            int idx = tid + 256 * j;
            int ab = idx >> 4, s = idx & 15;
            int a = ab >> 3, b = ab & 7;
            float acc = 0.f;
#pragma unroll
            for (int p = 0; p < 16; ++p)
                acc += T1s[a * 256 + p * 16 + s] * u2[(b * 8 + r) * 16 + p];
            T2s[ab * 17 + s] = acc;
        }
        __syncthreads();
        // W rows o = blk*4 + j ; thread covers cols [col0, col0+16)
        {
            const int j = tid >> 6;
            const int t = t0 + j;
            const int col0 = (tid & 63) * 16;
            const int ab = col0 >> 4;
            const float* t2p = &T2s[ab * 17];
            short* wrow = &Wb[(blk * 4 + j) * 1024 + col0];
            s16x8 v0, v1;
#pragma unroll
            for (int c = 0; c < 16; ++c) {
                const float* u3p = &u3[c * 256 + t * 16];
                float acc = 0.f;
#pragma unroll
                for (int s = 0; s < 16; ++s) acc += t2p[s] * u3p[s];
                short bf = f2bf(acc);
                if (c < 8) v0[c] = bf; else v1[c - 8] = bf;
            }
            *(s16x8*)(wrow) = v0;
            *(s16x8*)(wrow + 8) = v1;
        }
    }
    __threadfence();
    cg::this_grid().sync();

    // ================= Phase B: MFMA GEMM + fused fc2 ======================
    const int lane = tid & 63;
    const int w = tid >> 6, wr = w >> 1, wc = w & 1;
    const int z0 = (blk >> 4) * 64, o0 = (blk & 15) * 64;
    const int srow = tid >> 2;                 // 0..63
    const int sc = (tid & 3) * 16;             // col base; halves at +0,+64

    if (tid < 160) {                           // stage fc2_w tile [10][64]
        int jj = (tid * 4) >> 6, c = (tid * 4) & 63;
        *(float4*)&W2s[jj][c] = *(const float4*)&fc2w[jj * 1024 + o0 + c];
    }

    const float* xp = &x[(z0 + srow) * 1024 + sc];
    const short* wp = &Wb[(o0 + srow) * 1024 + sc];

    f32x4 acc[2][2] = {};
    float4 ax[8];
    s16x8 bx[4];

#pragma unroll
    for (int h = 0; h < 2; ++h) {
#pragma unroll
        for (int q = 0; q < 4; ++q) ax[h * 4 + q] = *(const float4*)(xp + h * 64 + q * 4);
#pragma unroll
        for (int q = 0; q < 2; ++q) bx[h * 2 + q] = *(const s16x8*)(wp + h * 64 + q * 8);
    }

    for (int k0 = 0; k0 < 1024; k0 += 128) {
        // regs -> LDS (convert X to bf16)
#pragma unroll
        for (int h = 0; h < 2; ++h) {
#pragma unroll
            for (int q = 0; q < 2; ++q) {
                float4 lo = ax[h * 4 + 2 * q], hi = ax[h * 4 + 2 * q + 1];
                s16x8 v;
                v[0] = f2bf(lo.x); v[1] = f2bf(lo.y);
                v[2] = f2bf(lo.z); v[3] = f2bf(lo.w);
                v[4] = f2bf(hi.x); v[5] = f2bf(hi.y);
                v[6] = f2bf(hi.z); v[7] = f2bf(hi.w);
                *(s16x8*)&As[srow][sc + h * 64 + q * 8] = v;
                *(s16x8*)&Bs[srow][sc + h * 64 + q * 8] = bx[h * 2 + q];
            }
        }
        __syncthreads();
        if (k0 + 128 < 1024) {                 // prefetch next K-tile
            const float* xi = xp + k0 + 128;
            const short* wi = wp + k0 + 128;
#pragma unroll
            for (int h = 0; h < 2; ++h) {
#pragma unroll
                for (int q = 0; q < 4; ++q) ax[h * 4 + q] = *(const float4*)(xi + h * 64 + q * 4);
#pragma unroll
                for (int q = 0; q < 2; ++q) bx[h * 2 + q] = *(const s16x8*)(wi + h * 64 + q * 8);
            }
        }
#pragma unroll
        for (int ks = 0; ks < 4; ++ks) {
            const int kb = ks * 32 + (lane >> 4) * 8;
            s16x8 a0 = *(const s16x8*)&As[wr * 32 + (lane & 15)][kb];
            s16x8 a1 = *(const s16x8*)&As[wr * 32 + 16 + (lane & 15)][kb];
            s16x8 b0 = *(const s16x8*)&Bs[wc * 32 + (lane & 15)][kb];
            s16x8 b1 = *(const s16x8*)&Bs[wc * 32 + 16 + (lane & 15)][kb];
            acc[0][0] = __builtin_amdgcn_mfma_f32_16x16x32_bf16(a0, b0, acc[0][0], 0, 0, 0);
            acc[0][1] = __builtin_amdgcn_mfma_f32_16x16x32_bf16(a0, b1, acc[0][1], 0, 0, 0);
            acc[1][0] = __builtin_amdgcn_mfma_f32_16x16x32_bf16(a1, b0, acc[1][0], 0, 0, 0);
            acc[1][1] = __builtin_amdgcn_mfma_f32_16x16x32_bf16(a1, b1, acc[1][1], 0, 0, 0);
        }
        __syncthreads();
    }

    // ---- epilogue: relu H-tile into LDS (alias As: 64 rows x 68 f32)
    float* Ht = (float*)As;
#pragma unroll
    for (int m = 0; m < 2; ++m) {
#pragma unroll
        for (int n = 0; n < 2; ++n) {
            const int row = wr * 32 + m * 16 + (lane >> 4) * 4;
            const int col = wc * 32 + n * 16 + (lane & 15);
            const float bv = bias1[o0 + col];
#pragma unroll
            for (int j = 0; j < 4; ++j)
                Ht[(row + j) * 68 + col] = fmaxf(acc[m][n][j] + bv, 0.f);
        }
    }
    __syncthreads();

    // ---- fused fc2: 4 threads per z-row, stride-4 interleaved cols
    const int rrow = tid >> 2, q = tid & 3;
    float part[10];
#pragma unroll
    for (int jj = 0; jj < 10; ++jj) part[jj] = 0.f;
#pragma unroll
    for (int cc = 0; cc < 16; ++cc) {
        const int c = q + 4 * cc;
        const float hv = Ht[rrow * 68 + c];
#pragma unroll
        for (int jj = 0; jj < 10; ++jj) part[jj] += hv * W2s[jj][c];
    }
#pragma unroll
    for (int jj = 0; jj < 10; ++jj) {
        float p = part[jj];
        p += __shfl_xor(p, 1);
        p += __shfl_xor(p, 2);
        if (q == 0) atomicAdd(&out[(z0 + rrow) * 10 + jj], p);
    }
}

extern "C" void kernel_launch(void* const* d_in, const int* in_sizes, int n_in,
                              void* d_out, int out_size, void* d_ws, size_t ws_size,
                              hipStream_t stream) {
    const float* x     = (const float*)d_in[0];
    const float* u1    = (const float*)d_in[1];
    const float* u2    = (const float*)d_in[2];
    const float* u3    = (const float*)d_in[3];
    const float* b2    = (const float*)d_in[4];
    const float* b1c   = (const float*)d_in[5];
    const float* bias1 = (const float*)d_in[6];
    const float* fc2w  = (const float*)d_in[7];
    const float* fc2b  = (const float*)d_in[8];
    float* out = (float*)d_out;
    short* Wb = (short*)d_ws;                  // 2 MB bf16 W_eff

    void* args[] = {(void*)&x, (void*)&u1, (void*)&u2, (void*)&u3,
                    (void*)&b2, (void*)&b1c, (void*)&bias1, (void*)&fc2w,
                    (void*)&fc2b, (void*)&Wb, (void*)&out};
    hipLaunchCooperativeKernel((void*)k_fused, dim3(256), dim3(256), args, 0,
                               stream);
}

// Round 5
// 31.617 us; speedup vs baseline: 3.1601x; 3.1601x over previous
//
#include <hip/hip_runtime.h>

// ---------------------------------------------------------------------------
// tNet: einsum chain is linear in x.
// Kernel 1 (grid 512): blocks 0..255 build 4 rows each of W_eff (1024x1024,
//   bf16) and init out=fc2_b; blocks 256..511 convert X f32->bf16 (Xb).
// Kernel 2: H-tile = relu(Xb @ W^T + bias1) via bf16 MFMA (64x64 tile,
//   BK=256, 4 waves 2x2, reg-prefetch double buffer), fused fc2 partials
//   -> atomicAdd(out).
//   t5[z,d,r,t] = sum_{a,b,c,e,p,q,s} x[z,a,b,c] u1[a,d,e] b2[e,p,q]
//                                     u2[b,r,p] b1c[q,s] u3[c,t,s]
//   o = d*128+r*16+t ; i = a*128+b*16+c
// Staged: C2[e,p,s]=sum_q b2*b1c ; T1[a,p,s]=sum_e u1[a*8+d]*C2 (d fixed);
//         T2[ab,s]=sum_p T1*u2 (r fixed) ; W[o,i]=sum_s T2*u3
// ---------------------------------------------------------------------------

using s16x8 = __attribute__((ext_vector_type(8))) short;   // 8 bf16
using f32x4 = __attribute__((ext_vector_type(4))) float;

__device__ inline short f2bf(float f) {
    unsigned u = __builtin_bit_cast(unsigned, f);
    u += 0x7fffu + ((u >> 16) & 1u);          // round-to-nearest-even
    return (short)(u >> 16);
}

// grid 512: blk<256 -> build W rows [blk*4, blk*4+4) + init out
//           blk>=256 -> convert 4096 elements of X to bf16
__global__ __launch_bounds__(256) void k_prep(
    const float* __restrict__ x, const float* __restrict__ u1,
    const float* __restrict__ u2, const float* __restrict__ u3,
    const float* __restrict__ b2, const float* __restrict__ b1c,
    const float* __restrict__ fc2b, short* __restrict__ Wb,
    short* __restrict__ Xb, float* __restrict__ out) {
    const int blk = blockIdx.x;
    const int tid = threadIdx.x;

    if (blk >= 256) {                          // X f32 -> bf16
        const int base = (blk - 256) * 4096 + tid * 16;
#pragma unroll
        for (int h = 0; h < 2; ++h) {
            float4 f0 = *(const float4*)&x[base + h * 8];
            float4 f1 = *(const float4*)&x[base + h * 8 + 4];
            s16x8 v;
            v[0] = f2bf(f0.x); v[1] = f2bf(f0.y);
            v[2] = f2bf(f0.z); v[3] = f2bf(f0.w);
            v[4] = f2bf(f1.x); v[5] = f2bf(f1.y);
            v[6] = f2bf(f1.z); v[7] = f2bf(f1.w);
            *(s16x8*)&Xb[base + h * 8] = v;
        }
        return;
    }

    __shared__ float C2f[4096];
    __shared__ float T1s[2048];
    __shared__ float T2s[64 * 17];
    const int d = blk >> 5;
    const int r = (blk >> 2) & 7;
    const int t0 = (blk & 3) * 4;

    if (tid < 40) {                            // out init: 256*40 = 10240
        int idx = blk * 40 + tid;
        out[idx] = fc2b[idx % 10];
    }
    // C2[e,p,s]
#pragma unroll
    for (int j = 0; j < 16; ++j) {
        int idx = tid + 256 * j;
        int p = (idx >> 4) & 15, s = idx & 15;
        float acc = 0.f;
#pragma unroll
        for (int q = 0; q < 16; ++q)
            acc += b2[j * 256 + p * 16 + q] * b1c[q * 16 + s];
        C2f[idx] = acc;
    }
    __syncthreads();
    // T1[a][p*16+s]  (d fixed)
#pragma unroll
    for (int j = 0; j < 8; ++j) {
        float acc = 0.f;
#pragma unroll
        for (int e = 0; e < 16; ++e)
            acc += u1[(j * 8 + d) * 16 + e] * C2f[e * 256 + tid];
        T1s[j * 256 + tid] = acc;
    }
    __syncthreads();
    // T2[ab][s] (r fixed), stride 17 kills bank conflicts
#pragma unroll
    for (int j = 0; j < 4; ++j) {
        int idx = tid + 256 * j;
        int ab = idx >> 4, s = idx & 15;
        int a = ab >> 3, b = ab & 7;
        float acc = 0.f;
#pragma unroll
        for (int p = 0; p < 16; ++p)
            acc += T1s[a * 256 + p * 16 + s] * u2[(b * 8 + r) * 16 + p];
        T2s[ab * 17 + s] = acc;
    }
    __syncthreads();
    // W rows o = blk*4 + j ; thread covers cols [col0, col0+16)
    {
        const int j = tid >> 6;
        const int t = t0 + j;
        const int col0 = (tid & 63) * 16;
        const int ab = col0 >> 4;
        const float* t2p = &T2s[ab * 17];
        short* wrow = &Wb[(blk * 4 + j) * 1024 + col0];
        s16x8 v0, v1;
#pragma unroll
        for (int c = 0; c < 16; ++c) {
            const float* u3p = &u3[c * 256 + t * 16];
            float acc = 0.f;
#pragma unroll
            for (int s = 0; s < 16; ++s) acc += t2p[s] * u3p[s];
            short bf = f2bf(acc);
            if (c < 8) v0[c] = bf; else v1[c - 8] = bf;
        }
        *(s16x8*)(wrow) = v0;
        *(s16x8*)(wrow + 8) = v1;
    }
}

// ---------------------------------------------------------------------------
// MFMA GEMM + fused fc2. 64x64 tile, BK=256 (4 K-iters, 8 barriers total),
// 4 waves (2x2), each wave 32x32 via 2x2 16x16x32 bf16 frags.
// LDS rows padded to 264 shorts (132 words, stride%32=4 -> 2-way alias, free).
// ---------------------------------------------------------------------------
#define LDK 264

__global__ __launch_bounds__(256) void k_gemm(
    const short* __restrict__ Xb, const short* __restrict__ Wb,
    const float* __restrict__ bias, const float* __restrict__ W2,
    float* __restrict__ out) {
    __shared__ short As[64][LDK];              // 33792 B
    __shared__ short Bs[64][LDK];              // 33792 B
    __shared__ float W2s[10][64];
    const int tid = threadIdx.x;
    const int lane = tid & 63;
    const int w = tid >> 6, wr = w >> 1, wc = w & 1;
    const int z0 = blockIdx.y * 64, o0 = blockIdx.x * 64;
    const int srow = tid >> 2;                 // 0..63, 4 threads/row
    const int sc = (tid & 3) * 16;             // 32 shorts/thread per 64-chunk

    if (tid < 160) {                           // stage fc2_w tile [10][64]
        int jj = (tid * 4) >> 6, c = (tid * 4) & 63;
        *(float4*)&W2s[jj][c] = *(const float4*)&W2[jj * 1024 + o0 + c];
    }

    const short* xp = &Xb[(z0 + srow) * 1024 + sc];
    const short* wp = &Wb[(o0 + srow) * 1024 + sc];

    f32x4 acc[2][2] = {};
    s16x8 ax[8], bx[8];                        // 4 halves x 2 chunks

#pragma unroll
    for (int h = 0; h < 4; ++h)
#pragma unroll
        for (int q = 0; q < 2; ++q) {
            ax[h * 2 + q] = *(const s16x8*)(xp + h * 64 + q * 8);
            bx[h * 2 + q] = *(const s16x8*)(wp + h * 64 + q * 8);
        }

    for (int k0 = 0; k0 < 1024; k0 += 256) {
        // regs -> LDS
#pragma unroll
        for (int h = 0; h < 4; ++h)
#pragma unroll
            for (int q = 0; q < 2; ++q) {
                *(s16x8*)&As[srow][sc + h * 64 + q * 8] = ax[h * 2 + q];
                *(s16x8*)&Bs[srow][sc + h * 64 + q * 8] = bx[h * 2 + q];
            }
        __syncthreads();
        if (k0 + 256 < 1024) {                 // prefetch next K-tile
            const short* xi = xp + k0 + 256;
            const short* wi = wp + k0 + 256;
#pragma unroll
            for (int h = 0; h < 4; ++h)
#pragma unroll
                for (int q = 0; q < 2; ++q) {
                    ax[h * 2 + q] = *(const s16x8*)(xi + h * 64 + q * 8);
                    bx[h * 2 + q] = *(const s16x8*)(wi + h * 64 + q * 8);
                }
        }
#pragma unroll
        for (int ks = 0; ks < 8; ++ks) {
            const int kb = ks * 32 + (lane >> 4) * 8;
            s16x8 a0 = *(const s16x8*)&As[wr * 32 + (lane & 15)][kb];
            s16x8 a1 = *(const s16x8*)&As[wr * 32 + 16 + (lane & 15)][kb];
            s16x8 b0 = *(const s16x8*)&Bs[wc * 32 + (lane & 15)][kb];
            s16x8 b1 = *(const s16x8*)&Bs[wc * 32 + 16 + (lane & 15)][kb];
            acc[0][0] = __builtin_amdgcn_mfma_f32_16x16x32_bf16(a0, b0, acc[0][0], 0, 0, 0);
            acc[0][1] = __builtin_amdgcn_mfma_f32_16x16x32_bf16(a0, b1, acc[0][1], 0, 0, 0);
            acc[1][0] = __builtin_amdgcn_mfma_f32_16x16x32_bf16(a1, b0, acc[1][0], 0, 0, 0);
            acc[1][1] = __builtin_amdgcn_mfma_f32_16x16x32_bf16(a1, b1, acc[1][1], 0, 0, 0);
        }
        __syncthreads();
    }

    // ---- epilogue: relu H-tile into LDS (alias As: 64 rows x 132 f32)
    float* Ht = (float*)As;
#pragma unroll
    for (int m = 0; m < 2; ++m)
#pragma unroll
        for (int n = 0; n < 2; ++n) {
            const int row = wr * 32 + m * 16 + (lane >> 4) * 4;
            const int col = wc * 32 + n * 16 + (lane & 15);
            const float bv = bias[o0 + col];
#pragma unroll
            for (int j = 0; j < 4; ++j)
                Ht[(row + j) * 132 + col] = fmaxf(acc[m][n][j] + bv, 0.f);
        }
    __syncthreads();

    // ---- fused fc2: 4 threads per z-row, stride-4 interleaved cols
    const int rrow = tid >> 2, q = tid & 3;
    float part[10];
#pragma unroll
    for (int jj = 0; jj < 10; ++jj) part[jj] = 0.f;
#pragma unroll
    for (int cc = 0; cc < 16; ++cc) {
        const int c = q + 4 * cc;
        const float hv = Ht[rrow * 132 + c];
#pragma unroll
        for (int jj = 0; jj < 10; ++jj) part[jj] += hv * W2s[jj][c];
    }
#pragma unroll
    for (int jj = 0; jj < 10; ++jj) {
        float p = part[jj];
        p += __shfl_xor(p, 1);
        p += __shfl_xor(p, 2);
        if (q == 0) atomicAdd(&out[(z0 + rrow) * 10 + jj], p);
    }
}

extern "C" void kernel_launch(void* const* d_in, const int* in_sizes, int n_in,
                              void* d_out, int out_size, void* d_ws, size_t ws_size,
                              hipStream_t stream) {
    const float* x     = (const float*)d_in[0];
    const float* u1    = (const float*)d_in[1];
    const float* u2    = (const float*)d_in[2];
    const float* u3    = (const float*)d_in[3];
    const float* b2    = (const float*)d_in[4];
    const float* b1c   = (const float*)d_in[5];
    const float* bias1 = (const float*)d_in[6];
    const float* fc2w  = (const float*)d_in[7];
    const float* fc2b  = (const float*)d_in[8];
    float* out = (float*)d_out;

    short* Wb = (short*)d_ws;                                  // 2 MB bf16
    short* Xb = (short*)((char*)d_ws + 2u * 1024u * 1024u);    // 2 MB bf16

    k_prep<<<512, 256, 0, stream>>>(x, u1, u2, u3, b2, b1c, fc2b, Wb, Xb, out);
    k_gemm<<<dim3(16, 16), 256, 0, stream>>>(Xb, Wb, bias1, fc2w, out);
}